// Round 7
// baseline (76.896 us; speedup 1.0000x reference)
//
#include <hip/hip_runtime.h>
#include <math.h>

// x = [32, 3, 512, 512] fp32. Output = concat(gabor flat, x flat), fp32.
constexpr int W_ = 512;
constexpr int H_ = 512;
constexpr int PLANE_ = W_ * H_;              // 262144
constexpr float S_ = 0.35355339059327373f;   // 1/(2*sqrt(2))
constexpr float PI_2 = 1.5707963267948966f;

typedef float f32x4 __attribute__((ext_vector_type(4)));

// Phase 1: x -> xout copy. Normal loads (pull x into L2/L3 for phase 2),
// nontemporal stores (xout is write-only, keep it out of the cache).
__global__ __launch_bounds__(256)
void copy_kernel(const f32x4* __restrict__ in, f32x4* __restrict__ out, int n4)
{
    int i = blockIdx.x * blockDim.x + threadIdx.x;
    const int stride = gridDim.x * blockDim.x;
    for (; i < n4; i += stride) {
        f32x4 v = in[i];
        __builtin_nontemporal_store(v, out + i);
    }
}

// atan(sqrt(s)/d) for s>=0, d>0, via rsq+rcp range reduction and a
// 2-FMA minimax polynomial (max err ~6e-4 rad; output budget is ~2 rad).
__device__ __forceinline__ float atan_mag(float s, float d)
{
    s = fmaxf(s, 1e-30f);                    // avoid 0*inf -> NaN
    float r  = __builtin_amdgcn_rsqf(s);     // 1/sqrt(s)
    float rd = __builtin_amdgcn_rcpf(d);     // 1/d
    float t  = s * r * rd;                   // sqrt(s)/d
    float it = d * r;                        // 1/t
    float tt = fminf(t, it);                 // reduce to [0,1]
    float u  = tt * tt;
    float p  = tt * fmaf(u, fmaf(u, 0.079331f, -0.288679f), 0.995354f);
    return (t > 1.0f) ? (PI_2 - p) : p;
}

// KX = [[-S,0,S],[-1,0,1],[-S,0,S]], KY = [[S,1,S],[0,0,0],[-S,-1,-S]]
// (XLA conv = cross-correlation, no flip). out = atan(mag)*a1 + a0.
__device__ __forceinline__ float gab(float tl, float tc, float tr,
                                     float ml, float mc, float mr,
                                     float bl, float bc, float br,
                                     float a1, float a0)
{
    float gx = fmaf(S_, (tr - tl) + (br - bl), mr - ml);
    float gy = fmaf(S_, (tl + tr) - (bl + br), tc - bc);
    float s  = fmaf(gx, gx, gy * gy);
    float den = mc + 0.001f;
    return fmaf(atan_mag(s, den), a1, a0);
}

// Phase 2: gabor only (no xout stores). R5 structure otherwise:
// 8-wide x 2-row tile per thread, predicated scalar halo loads.
__global__ __launch_bounds__(256)
void gabor_kernel(const float* __restrict__ x,
                  float* __restrict__ gout)
{
    const int lane  = threadIdx.x & 63;
    const int wv    = threadIdx.x >> 6;          // 0..3
    const int bid   = blockIdx.x;
    const int plane = bid >> 6;                  // 96 planes, 64 blocks/plane
    const int hp    = ((bid & 63) << 2) | wv;    // row-pair index 0..255
    const int h0    = hp << 1;                   // even output row
    const int w0    = lane << 3;                 // 8-wide chunk start

    const size_t pbase = (size_t)plane * PLANE_;
    const float* row0 = x + pbase + (size_t)h0 * W_ + w0;

    // rows: r0 = h0-1 (pad), r1 = h0, r2 = h0+1, r3 = h0+2 (pad)
    // [0]=left halo, [1..8]=center 8, [9]=right halo
    float r0[10], r1[10], r2[10], r3[10];

#define LOADROW(dst, r)                                               \
    {                                                                 \
        f32x4 a = *reinterpret_cast<const f32x4*>(r);                 \
        f32x4 b = *reinterpret_cast<const f32x4*>((r) + 4);           \
        dst[1] = a.x; dst[2] = a.y; dst[3] = a.z; dst[4] = a.w;       \
        dst[5] = b.x; dst[6] = b.y; dst[7] = b.z; dst[8] = b.w;       \
        dst[0] = (lane > 0)  ? (r)[-1] : 0.0f;                        \
        dst[9] = (lane < 63) ? (r)[8]  : 0.0f;                        \
    }

    LOADROW(r1, row0)
    LOADROW(r2, row0 + W_)
    if (h0 > 0) {                 // wave-uniform branch
        LOADROW(r0, row0 - W_)
    } else {
        #pragma unroll
        for (int i = 0; i < 10; ++i) r0[i] = 0.0f;
    }
    if (h0 < H_ - 2) {            // wave-uniform branch
        LOADROW(r3, row0 + 2 * W_)
    } else {
        #pragma unroll
        for (int i = 0; i < 10; ++i) r3[i] = 0.0f;
    }
#undef LOADROW

    const int c = plane % 3;   // wave-uniform
    const float invstd = (c == 0) ? (1.0f/0.229f) : (c == 1 ? (1.0f/0.224f) : (1.0f/0.225f));
    const float mean   = (c == 0) ? 0.485f        : (c == 1 ? 0.456f        : 0.406f);
    const float a1 = invstd * (1.0f / 255.0f);
    const float a0 = -mean * invstd;

    float ga[8], gb[8];
    #pragma unroll
    for (int j = 1; j <= 8; ++j)
        ga[j-1] = gab(r0[j-1], r0[j], r0[j+1],
                      r1[j-1], r1[j], r1[j+1],
                      r2[j-1], r2[j], r2[j+1], a1, a0);
    #pragma unroll
    for (int j = 1; j <= 8; ++j)
        gb[j-1] = gab(r1[j-1], r1[j], r1[j+1],
                      r2[j-1], r2[j], r2[j+1],
                      r3[j-1], r3[j], r3[j+1], a1, a0);

    const size_t o0 = pbase + (size_t)h0 * W_ + w0;
    const size_t o1 = o0 + W_;

#define NTSTORE(p, a, b, cc, d)                                       \
    {                                                                 \
        f32x4 v_; v_.x = (a); v_.y = (b); v_.z = (cc); v_.w = (d);    \
        __builtin_nontemporal_store(v_, reinterpret_cast<f32x4*>(p)); \
    }
    NTSTORE(gout + o0,     ga[0], ga[1], ga[2], ga[3])
    NTSTORE(gout + o0 + 4, ga[4], ga[5], ga[6], ga[7])
    NTSTORE(gout + o1,     gb[0], gb[1], gb[2], gb[3])
    NTSTORE(gout + o1 + 4, gb[4], gb[5], gb[6], gb[7])
#undef NTSTORE
}

extern "C" void kernel_launch(void* const* d_in, const int* in_sizes, int n_in,
                              void* d_out, int out_size, void* d_ws, size_t ws_size,
                              hipStream_t stream) {
    const float* x = (const float*)d_in[0];
    float* out = (float*)d_out;
    const int n_elem = in_sizes[0];          // 25165824
    float* gout = out;
    float* xout = out + n_elem;

    // Phase 1: passthrough copy; pulls x into L3, streams xout out NT.
    const int n4 = n_elem / 4;               // 6291456
    copy_kernel<<<4096, 256, 0, stream>>>(
        reinterpret_cast<const f32x4*>(x), reinterpret_cast<f32x4*>(xout), n4);

    // Phase 2: gabor, reading L3-hot x, writing only gout.
    const int grid = 96 * 64;                // 6144 blocks, 4 waves each
    gabor_kernel<<<grid, 256, 0, stream>>>(x, gout);
}

// Round 8
// 61.382 us; speedup vs baseline: 1.2527x; 1.2527x over previous
//
#include <hip/hip_runtime.h>
#include <math.h>

// x = [32, 3, 512, 512] fp32. Output = concat(gabor flat, x flat), fp32.
// R8 = R1 fine-grained structure (4 px/thread) + NT stores + cheap atan.
constexpr int W_ = 512;
constexpr int H_ = 512;
constexpr int PLANE_ = W_ * H_;          // 262144
constexpr int VEC_PER_ROW = W_ / 4;      // 128
constexpr float S_ = 0.35355339059327373f;   // 1/(2*sqrt(2))
constexpr float PI_2 = 1.5707963267948966f;

typedef float f32x4 __attribute__((ext_vector_type(4)));

// atan(sqrt(s)/d) for s>=0, d>0 (max err ~6e-4 rad; budget ~2 rad).
__device__ __forceinline__ float atan_mag(float s, float d)
{
    s = fmaxf(s, 1e-30f);
    float r  = __builtin_amdgcn_rsqf(s);
    float rd = __builtin_amdgcn_rcpf(d);
    float t  = s * r * rd;                   // sqrt(s)/d
    float it = d * r;                        // 1/t
    float tt = fminf(t, it);
    float u  = tt * tt;
    float p  = tt * fmaf(u, fmaf(u, 0.079331f, -0.288679f), 0.995354f);
    return (t > 1.0f) ? (PI_2 - p) : p;
}

__global__ __launch_bounds__(256)
void gabor_kernel(const float* __restrict__ x,
                  float* __restrict__ gout,
                  float* __restrict__ xout,
                  int total_vec)
{
    int idx = blockIdx.x * blockDim.x + threadIdx.x;
    if (idx >= total_vec) return;

    const int w4    = idx & (VEC_PER_ROW - 1);   // vec4 index within row
    const int h     = (idx >> 7) & (H_ - 1);     // row
    const int plane = idx >> 16;                 // n*3 + c
    const int c     = plane % 3;                 // wave-uniform
    const int w0    = w4 << 2;

    const float* base = x + (size_t)plane * PLANE_ + (size_t)h * W_ + w0;

    // [0]=left halo, [1..4]=center vec4, [5]=right halo
    float t_[6], m_[6], b_[6];

    {
        f32x4 v = *reinterpret_cast<const f32x4*>(base);
        m_[1] = v.x; m_[2] = v.y; m_[3] = v.z; m_[4] = v.w;
        m_[0] = (w4 > 0)               ? base[-1] : 0.0f;
        m_[5] = (w4 < VEC_PER_ROW - 1) ? base[4]  : 0.0f;
    }
    if (h > 0) {
        const float* r = base - W_;
        f32x4 v = *reinterpret_cast<const f32x4*>(r);
        t_[1] = v.x; t_[2] = v.y; t_[3] = v.z; t_[4] = v.w;
        t_[0] = (w4 > 0)               ? r[-1] : 0.0f;
        t_[5] = (w4 < VEC_PER_ROW - 1) ? r[4]  : 0.0f;
    } else {
        #pragma unroll
        for (int i = 0; i < 6; ++i) t_[i] = 0.0f;
    }
    if (h < H_ - 1) {
        const float* r = base + W_;
        f32x4 v = *reinterpret_cast<const f32x4*>(r);
        b_[1] = v.x; b_[2] = v.y; b_[3] = v.z; b_[4] = v.w;
        b_[0] = (w4 > 0)               ? r[-1] : 0.0f;
        b_[5] = (w4 < VEC_PER_ROW - 1) ? r[4]  : 0.0f;
    } else {
        #pragma unroll
        for (int i = 0; i < 6; ++i) b_[i] = 0.0f;
    }

    const float invstd = (c == 0) ? (1.0f/0.229f) : (c == 1 ? (1.0f/0.224f) : (1.0f/0.225f));
    const float mean   = (c == 0) ? 0.485f        : (c == 1 ? 0.456f        : 0.406f);
    const float a1 = invstd * (1.0f / 255.0f);
    const float a0 = -mean * invstd;

    float res[4];
    #pragma unroll
    for (int j = 0; j < 4; ++j) {
        // KX = [[-S,0,S],[-1,0,1],[-S,0,S]], KY = [[S,1,S],[0,0,0],[-S,-1,-S]]
        float gx = fmaf(S_, (t_[j+2] - t_[j]) + (b_[j+2] - b_[j]), m_[j+2] - m_[j]);
        float gy = fmaf(S_, (t_[j] + t_[j+2]) - (b_[j] + b_[j+2]), t_[j+1] - b_[j+1]);
        float s  = fmaf(gx, gx, gy * gy);
        float den = m_[j+1] + 0.001f;
        res[j] = fmaf(atan_mag(s, den), a1, a0);
    }

    f32x4 gv; gv.x = res[0]; gv.y = res[1]; gv.z = res[2]; gv.w = res[3];
    f32x4 xv; xv.x = m_[1]; xv.y = m_[2]; xv.z = m_[3]; xv.w = m_[4];
    __builtin_nontemporal_store(gv, reinterpret_cast<f32x4*>(gout + ((size_t)idx << 2)));
    __builtin_nontemporal_store(xv, reinterpret_cast<f32x4*>(xout + ((size_t)idx << 2)));
}

extern "C" void kernel_launch(void* const* d_in, const int* in_sizes, int n_in,
                              void* d_out, int out_size, void* d_ws, size_t ws_size,
                              hipStream_t stream) {
    const float* x = (const float*)d_in[0];
    float* out = (float*)d_out;
    const int n_elem = in_sizes[0];          // 25165824
    const int total_vec = n_elem / 4;        // 6291456
    float* gout = out;
    float* xout = out + n_elem;

    const int block = 256;
    const int grid = (total_vec + block - 1) / block;   // 24576 blocks
    gabor_kernel<<<grid, block, 0, stream>>>(x, gout, xout, total_vec);
}

// Round 9
// 53.008 us; speedup vs baseline: 1.4507x; 1.1580x over previous
//
#include <hip/hip_runtime.h>
#include <math.h>

// x = [32, 3, 512, 512] fp32. Output = concat(gabor flat, x flat), fp32.
// R9 = R8 (fine 4px/thread + NT stores + cheap atan) + isolated XCD-band
// swizzle: each XCD gets a contiguous band of blocks so vertically-adjacent
// blocks (which share halo rows) co-run on the same XCD's L2.
constexpr int W_ = 512;
constexpr int H_ = 512;
constexpr int PLANE_ = W_ * H_;          // 262144
constexpr int VEC_PER_ROW = W_ / 4;      // 128
constexpr float S_ = 0.35355339059327373f;   // 1/(2*sqrt(2))
constexpr float PI_2 = 1.5707963267948966f;

typedef float f32x4 __attribute__((ext_vector_type(4)));

// atan(sqrt(s)/d) for s>=0, d>0 (max err ~6e-4 rad; budget ~2 rad).
__device__ __forceinline__ float atan_mag(float s, float d)
{
    s = fmaxf(s, 1e-30f);
    float r  = __builtin_amdgcn_rsqf(s);
    float rd = __builtin_amdgcn_rcpf(d);
    float t  = s * r * rd;                   // sqrt(s)/d
    float it = d * r;                        // 1/t
    float tt = fminf(t, it);
    float u  = tt * tt;
    float p  = tt * fmaf(u, fmaf(u, 0.079331f, -0.288679f), 0.995354f);
    return (t > 1.0f) ? (PI_2 - p) : p;
}

__global__ __launch_bounds__(256)
void gabor_kernel(const float* __restrict__ x,
                  float* __restrict__ gout,
                  float* __restrict__ xout)
{
    // XCD-band swizzle: 24576 blocks, 8 XCDs -> 3072 contiguous logical
    // blocks per XCD (assumes round-robin hw dispatch; bijective since
    // 24576 % 8 == 0). Perf-only: any mapping is correct.
    const int idx = ((blockIdx.x & 7) * 3072 + (blockIdx.x >> 3)) * 256
                    + threadIdx.x;

    const int w4    = idx & (VEC_PER_ROW - 1);   // vec4 index within row
    const int h     = (idx >> 7) & (H_ - 1);     // row
    const int plane = idx >> 16;                 // n*3 + c
    const int c     = plane % 3;                 // wave-uniform
    const int w0    = w4 << 2;

    const float* base = x + (size_t)plane * PLANE_ + (size_t)h * W_ + w0;

    // [0]=left halo, [1..4]=center vec4, [5]=right halo
    float t_[6], m_[6], b_[6];

    {
        f32x4 v = *reinterpret_cast<const f32x4*>(base);
        m_[1] = v.x; m_[2] = v.y; m_[3] = v.z; m_[4] = v.w;
        m_[0] = (w4 > 0)               ? base[-1] : 0.0f;
        m_[5] = (w4 < VEC_PER_ROW - 1) ? base[4]  : 0.0f;
    }
    if (h > 0) {
        const float* r = base - W_;
        f32x4 v = *reinterpret_cast<const f32x4*>(r);
        t_[1] = v.x; t_[2] = v.y; t_[3] = v.z; t_[4] = v.w;
        t_[0] = (w4 > 0)               ? r[-1] : 0.0f;
        t_[5] = (w4 < VEC_PER_ROW - 1) ? r[4]  : 0.0f;
    } else {
        #pragma unroll
        for (int i = 0; i < 6; ++i) t_[i] = 0.0f;
    }
    if (h < H_ - 1) {
        const float* r = base + W_;
        f32x4 v = *reinterpret_cast<const f32x4*>(r);
        b_[1] = v.x; b_[2] = v.y; b_[3] = v.z; b_[4] = v.w;
        b_[0] = (w4 > 0)               ? r[-1] : 0.0f;
        b_[5] = (w4 < VEC_PER_ROW - 1) ? r[4]  : 0.0f;
    } else {
        #pragma unroll
        for (int i = 0; i < 6; ++i) b_[i] = 0.0f;
    }

    const float invstd = (c == 0) ? (1.0f/0.229f) : (c == 1 ? (1.0f/0.224f) : (1.0f/0.225f));
    const float mean   = (c == 0) ? 0.485f        : (c == 1 ? 0.456f        : 0.406f);
    const float a1 = invstd * (1.0f / 255.0f);
    const float a0 = -mean * invstd;

    float res[4];
    #pragma unroll
    for (int j = 0; j < 4; ++j) {
        // KX = [[-S,0,S],[-1,0,1],[-S,0,S]], KY = [[S,1,S],[0,0,0],[-S,-1,-S]]
        float gx = fmaf(S_, (t_[j+2] - t_[j]) + (b_[j+2] - b_[j]), m_[j+2] - m_[j]);
        float gy = fmaf(S_, (t_[j] + t_[j+2]) - (b_[j] + b_[j+2]), t_[j+1] - b_[j+1]);
        float s  = fmaf(gx, gx, gy * gy);
        float den = m_[j+1] + 0.001f;
        res[j] = fmaf(atan_mag(s, den), a1, a0);
    }

    f32x4 gv; gv.x = res[0]; gv.y = res[1]; gv.z = res[2]; gv.w = res[3];
    f32x4 xv; xv.x = m_[1]; xv.y = m_[2]; xv.z = m_[3]; xv.w = m_[4];
    __builtin_nontemporal_store(gv, reinterpret_cast<f32x4*>(gout + ((size_t)idx << 2)));
    __builtin_nontemporal_store(xv, reinterpret_cast<f32x4*>(xout + ((size_t)idx << 2)));
}

extern "C" void kernel_launch(void* const* d_in, const int* in_sizes, int n_in,
                              void* d_out, int out_size, void* d_ws, size_t ws_size,
                              hipStream_t stream) {
    const float* x = (const float*)d_in[0];
    float* out = (float*)d_out;
    const int n_elem = in_sizes[0];          // 25165824
    float* gout = out;
    float* xout = out + n_elem;

    const int block = 256;
    const int grid = (n_elem / 4) / block;   // 24576 blocks, exact
    gabor_kernel<<<grid, block, 0, stream>>>(x, gout, xout);
}

// Round 10
// 52.733 us; speedup vs baseline: 1.4582x; 1.0052x over previous
//
#include <hip/hip_runtime.h>
#include <math.h>

// x = [32, 3, 512, 512] fp32. Output = concat(gabor flat, x flat), fp32.
// R10 = R9 (fine 4px/thread + NT stores + cheap atan + XCD band swizzle)
// with 512-thread blocks: each block covers 4 rows (center) + 2 halo rows
// -> read-request amplification 1.5x instead of 2.0x.
constexpr int W_ = 512;
constexpr int H_ = 512;
constexpr int PLANE_ = W_ * H_;          // 262144
constexpr int VEC_PER_ROW = W_ / 4;      // 128
constexpr float S_ = 0.35355339059327373f;   // 1/(2*sqrt(2))
constexpr float PI_2 = 1.5707963267948966f;

typedef float f32x4 __attribute__((ext_vector_type(4)));

// atan(sqrt(s)/d) for s>=0, d>0 (max err ~6e-4 rad; budget ~2 rad).
__device__ __forceinline__ float atan_mag(float s, float d)
{
    s = fmaxf(s, 1e-30f);
    float r  = __builtin_amdgcn_rsqf(s);
    float rd = __builtin_amdgcn_rcpf(d);
    float t  = s * r * rd;                   // sqrt(s)/d
    float it = d * r;                        // 1/t
    float tt = fminf(t, it);
    float u  = tt * tt;
    float p  = tt * fmaf(u, fmaf(u, 0.079331f, -0.288679f), 0.995354f);
    return (t > 1.0f) ? (PI_2 - p) : p;
}

__global__ __launch_bounds__(512)
void gabor_kernel(const float* __restrict__ x,
                  float* __restrict__ gout,
                  float* __restrict__ xout)
{
    // XCD-band swizzle: 12288 blocks, 8 XCDs -> 1536 contiguous logical
    // blocks per XCD (bijective since 12288 % 8 == 0). Perf-only.
    const int idx = ((blockIdx.x & 7) * 1536 + (blockIdx.x >> 3)) * 512
                    + threadIdx.x;

    const int w4    = idx & (VEC_PER_ROW - 1);   // vec4 index within row
    const int h     = (idx >> 7) & (H_ - 1);     // row
    const int plane = idx >> 16;                 // n*3 + c
    const int c     = plane % 3;                 // wave-uniform
    const int w0    = w4 << 2;

    const float* base = x + (size_t)plane * PLANE_ + (size_t)h * W_ + w0;

    // [0]=left halo, [1..4]=center vec4, [5]=right halo
    float t_[6], m_[6], b_[6];

    {
        f32x4 v = *reinterpret_cast<const f32x4*>(base);
        m_[1] = v.x; m_[2] = v.y; m_[3] = v.z; m_[4] = v.w;
        m_[0] = (w4 > 0)               ? base[-1] : 0.0f;
        m_[5] = (w4 < VEC_PER_ROW - 1) ? base[4]  : 0.0f;
    }
    if (h > 0) {
        const float* r = base - W_;
        f32x4 v = *reinterpret_cast<const f32x4*>(r);
        t_[1] = v.x; t_[2] = v.y; t_[3] = v.z; t_[4] = v.w;
        t_[0] = (w4 > 0)               ? r[-1] : 0.0f;
        t_[5] = (w4 < VEC_PER_ROW - 1) ? r[4]  : 0.0f;
    } else {
        #pragma unroll
        for (int i = 0; i < 6; ++i) t_[i] = 0.0f;
    }
    if (h < H_ - 1) {
        const float* r = base + W_;
        f32x4 v = *reinterpret_cast<const f32x4*>(r);
        b_[1] = v.x; b_[2] = v.y; b_[3] = v.z; b_[4] = v.w;
        b_[0] = (w4 > 0)               ? r[-1] : 0.0f;
        b_[5] = (w4 < VEC_PER_ROW - 1) ? r[4]  : 0.0f;
    } else {
        #pragma unroll
        for (int i = 0; i < 6; ++i) b_[i] = 0.0f;
    }

    const float invstd = (c == 0) ? (1.0f/0.229f) : (c == 1 ? (1.0f/0.224f) : (1.0f/0.225f));
    const float mean   = (c == 0) ? 0.485f        : (c == 1 ? 0.456f        : 0.406f);
    const float a1 = invstd * (1.0f / 255.0f);
    const float a0 = -mean * invstd;

    float res[4];
    #pragma unroll
    for (int j = 0; j < 4; ++j) {
        // KX = [[-S,0,S],[-1,0,1],[-S,0,S]], KY = [[S,1,S],[0,0,0],[-S,-1,-S]]
        float gx = fmaf(S_, (t_[j+2] - t_[j]) + (b_[j+2] - b_[j]), m_[j+2] - m_[j]);
        float gy = fmaf(S_, (t_[j] + t_[j+2]) - (b_[j] + b_[j+2]), t_[j+1] - b_[j+1]);
        float s  = fmaf(gx, gx, gy * gy);
        float den = m_[j+1] + 0.001f;
        res[j] = fmaf(atan_mag(s, den), a1, a0);
    }

    f32x4 gv; gv.x = res[0]; gv.y = res[1]; gv.z = res[2]; gv.w = res[3];
    f32x4 xv; xv.x = m_[1]; xv.y = m_[2]; xv.z = m_[3]; xv.w = m_[4];
    __builtin_nontemporal_store(gv, reinterpret_cast<f32x4*>(gout + ((size_t)idx << 2)));
    __builtin_nontemporal_store(xv, reinterpret_cast<f32x4*>(xout + ((size_t)idx << 2)));
}

extern "C" void kernel_launch(void* const* d_in, const int* in_sizes, int n_in,
                              void* d_out, int out_size, void* d_ws, size_t ws_size,
                              hipStream_t stream) {
    const float* x = (const float*)d_in[0];
    float* out = (float*)d_out;
    const int n_elem = in_sizes[0];          // 25165824
    float* gout = out;
    float* xout = out + n_elem;

    const int block = 512;
    const int grid = (n_elem / 4) / block;   // 12288 blocks, exact
    gabor_kernel<<<grid, block, 0, stream>>>(x, gout, xout);
}